// Round 12
// baseline (64.548 us; speedup 1.0000x reference)
//
#include <hip/hip_runtime.h>
#include <math.h>

#define FLOOR_EPS 1e-12f

constexpr int B = 64, T = 8000, C = 80;
constexpr int C4   = C / 4;            // 20 float4 per timestep row
constexpr int SUB  = 25;               // timesteps per thread row
constexpr int WARM = 6;                // warmup rows: 150 steps, q^150 ~ 2.2e-3
constexpr int OUT  = 20;               // output rows (was 10: halves amplification)
constexpr int NSUB = WARM + OUT;       // 26 rows
constexpr int SEG  = OUT * SUB;        // 500 output timesteps per block
constexpr int NSEG = T / SEG;          // 16
constexpr int NTHREADS = NSUB * C4;    // 520 threads (8.125 waves; ~1% ragged)
constexpr int NBLOCKS  = NSEG * B;     // 1024 = exactly 4/CU, zero tail

typedef float f32x4 __attribute__((ext_vector_type(4)));

__device__ __forceinline__ float fexp2(float x) {
#if __has_builtin(__builtin_amdgcn_exp2f)
    return __builtin_amdgcn_exp2f(x);
#else
    return exp2f(x);
#endif
}
__device__ __forceinline__ float flog2(float x) {
#if __has_builtin(__builtin_amdgcn_logf)
    return __builtin_amdgcn_logf(x);
#else
    return log2f(x);
#endif
}
__device__ __forceinline__ float clamp01(float v) {
    return fminf(fmaxf(v, 0.0f), 1.0f);
}

// Round-9/11 machinery (burst loads, ONE barrier, flat parallel lookback,
// NT stores) with geometry retuned for traffic:
//   OUT 10 -> 20 at same WARM=6: read amplification 1.6x -> 1.3x
//   (-49 MB L3/fabric reads per call, -19% phase-A FMA),
//   warm-row waste 37.5% -> 23%, 1024 blocks = exactly 4/CU.
__global__ __launch_bounds__(NTHREADS, 3) void pcen_seg(
    const float* __restrict__ x,
    const float* __restrict__ weights,
    const float* __restrict__ alpha,
    const float* __restrict__ delta,
    const float* __restrict__ root,
    float* __restrict__ out)
{
    __shared__ float4 sP[NSUB][C4];   // 8.3 KB

    const int bid  = (int)blockIdx.x;
    const int b    = bid % B;
    const int kseg = bid / B;
    const int tid  = (int)threadIdx.x;
    const int g    = tid % C4;        // channel quad
    const int s    = tid / C4;        // row 0..25
    const int c    = g * 4;

    float4 w, q;
    {
        float wv;
        wv = clamp01(weights[c + 0]); w.x = wv; q.x = 1.0f - wv;
        wv = clamp01(weights[c + 1]); w.y = wv; q.y = 1.0f - wv;
        wv = clamp01(weights[c + 2]); w.z = wv; q.z = 1.0f - wv;
        wv = clamp01(weights[c + 3]); w.w = wv; q.w = 1.0f - wv;
    }

    const int t0 = kseg * SEG;
    const float4* xrow = reinterpret_cast<const float4*>(x + (size_t)b * T * C) + g;
    float4*       orow = reinterpret_cast<float4*>(out + (size_t)b * T * C) + g;

    const int ts = t0 - WARM * SUB + s * SUB;       // this row's window start
    const bool active = !(kseg == 0 && s < WARM);   // t<0 rows: partial = 0

    // ---- Burst-load the window (25 independent loads in flight) ----
    float4 xv[SUB];
    if (active) {
        #pragma unroll
        for (int t = 0; t < SUB; ++t)
            xv[t] = xrow[(ts + t) * C4];
    }

    // ---- Phase A: local zero-carry EMA partial ----
    float4 l = make_float4(0.f, 0.f, 0.f, 0.f);
    if (active) {
        if (kseg == 0 && s == WARM) l = xv[0];      // reference init e0 = x[:,0,:]
        #pragma unroll
        for (int t = 0; t < SUB; ++t) {
            float4 xvt = xv[t];
            l.x = fmaf(w.x, xvt.x, q.x * l.x);
            l.y = fmaf(w.y, xvt.y, q.y * l.y);
            l.z = fmaf(w.z, xvt.z, q.z * l.z);
            l.w = fmaf(w.w, xvt.w, q.w * l.w);
        }
    }
    sP[s][g] = l;

    // Hoisted per-channel params + per-row decay (overlap with barrier).
    float4 D;
    D.x = fexp2((float)SUB * flog2(q.x));
    D.y = fexp2((float)SUB * flog2(q.y));
    D.z = fexp2((float)SUB * flog2(q.z));
    D.w = fexp2((float)SUB * flog2(q.w));
    float4 a, oor, d, dpow;
    {
        float av, rv, dv;
        av = fminf(alpha[c + 0], 1.0f); a.x = av;
        av = fminf(alpha[c + 1], 1.0f); a.y = av;
        av = fminf(alpha[c + 2], 1.0f); a.z = av;
        av = fminf(alpha[c + 3], 1.0f); a.w = av;
        rv = fmaxf(root[c + 0], 1.0f); oor.x = 1.0f / rv;
        rv = fmaxf(root[c + 1], 1.0f); oor.y = 1.0f / rv;
        rv = fmaxf(root[c + 2], 1.0f); oor.z = 1.0f / rv;
        rv = fmaxf(root[c + 3], 1.0f); oor.w = 1.0f / rv;
        dv = delta[c + 0]; d.x = dv; dpow.x = fexp2(oor.x * flog2(dv));
        dv = delta[c + 1]; d.y = dv; dpow.y = fexp2(oor.y * flog2(dv));
        dv = delta[c + 2]; d.z = dv; dpow.z = fexp2(oor.z * flog2(dv));
        dv = delta[c + 3]; d.w = dv; dpow.w = fexp2(oor.w * flog2(dv));
    }
    __syncthreads();   // the ONLY barrier

    // ---- Warmup rows are done: they only publish partials ----
    if (s < WARM) return;

    // ---- Flat parallel lookback: cy = sum_{j<s} D^(s-1-j) * p_j ----
    float4 e = make_float4(0.f, 0.f, 0.f, 0.f);
    for (int j = 0; j < s; ++j) {
        float4 p = sP[j][g];
        e.x = fmaf(D.x, e.x, p.x);
        e.y = fmaf(D.y, e.y, p.y);
        e.z = fmaf(D.z, e.z, p.z);
        e.w = fmaf(D.w, e.w, p.w);
    }
    if (kseg == 0 && s == WARM) e = xv[0];   // exact init for the t=0 row

    // ---- Phase B: re-run EMA from carry + fused PCEN output ----
    #pragma unroll
    for (int t = 0; t < SUB; ++t) {
        float4 xvt = xv[t];
        e.x = fmaf(w.x, xvt.x, q.x * e.x);
        e.y = fmaf(w.y, xvt.y, q.y * e.y);
        e.z = fmaf(w.z, xvt.z, q.z * e.z);
        e.w = fmaf(w.w, xvt.w, q.w * e.w);

        float4 o;
        float inner;
        inner = fmaf(xvt.x, fexp2(-a.x * flog2(FLOOR_EPS + e.x)), d.x);
        o.x = fexp2(oor.x * flog2(inner)) - dpow.x;
        inner = fmaf(xvt.y, fexp2(-a.y * flog2(FLOOR_EPS + e.y)), d.y);
        o.y = fexp2(oor.y * flog2(inner)) - dpow.y;
        inner = fmaf(xvt.z, fexp2(-a.z * flog2(FLOOR_EPS + e.z)), d.z);
        o.z = fexp2(oor.z * flog2(inner)) - dpow.z;
        inner = fmaf(xvt.w, fexp2(-a.w * flog2(FLOOR_EPS + e.w)), d.w);
        o.w = fexp2(oor.w * flog2(inner)) - dpow.w;

        // NT store: out is never re-read; keep L3 for x.
        union { float4 f4; f32x4 v; } u;
        u.f4 = o;
        __builtin_nontemporal_store(
            u.v, reinterpret_cast<f32x4*>(&orow[(ts + t) * C4]));
    }
}

extern "C" void kernel_launch(void* const* d_in, const int* in_sizes, int n_in,
                              void* d_out, int out_size, void* d_ws, size_t ws_size,
                              hipStream_t stream) {
    const float* x       = (const float*)d_in[0];
    const float* weights = (const float*)d_in[1];
    const float* alpha   = (const float*)d_in[2];
    const float* delta   = (const float*)d_in[3];
    const float* root    = (const float*)d_in[4];
    float* out = (float*)d_out;

    dim3 blk(NTHREADS);
    dim3 grd(NBLOCKS);
    pcen_seg<<<grd, blk, 0, stream>>>(x, weights, alpha, delta, root, out);
}

// Round 13
// 55.282 us; speedup vs baseline: 1.1676x; 1.1676x over previous
//
#include <hip/hip_runtime.h>
#include <math.h>

#define FLOOR_EPS 1e-12f

constexpr int B = 64, T = 8000, C = 80;
constexpr int C4   = C / 4;            // 20 float4 per timestep row
constexpr int SUB  = 25;               // timesteps per thread row (reg-resident)
constexpr int WARM = 6;                // warmup rows: 150 steps, q^150 ~ 2.2e-3
constexpr int OUT  = 10;               // output rows
constexpr int NSUB = WARM + OUT;       // 16 rows
constexpr int SEG  = OUT * SUB;        // 250 output timesteps per block
constexpr int NSEG = T / SEG;          // 32
constexpr int NTHREADS = NSUB * C4;    // 320 = 5 waves exactly
constexpr int NBLOCKS  = NSEG * B;     // 2048 = 256 CU x 8: zero tail

typedef float f32x4 __attribute__((ext_vector_type(4)));

__device__ __forceinline__ float fexp2(float x) {
#if __has_builtin(__builtin_amdgcn_exp2f)
    return __builtin_amdgcn_exp2f(x);
#else
    return exp2f(x);
#endif
}
__device__ __forceinline__ float flog2(float x) {
#if __has_builtin(__builtin_amdgcn_logf)
    return __builtin_amdgcn_logf(x);
#else
    return log2f(x);
#endif
}
__device__ __forceinline__ float clamp01(float v) {
    return fminf(fmaxf(v, 0.0f), 1.0f);
}

// ROUND-9 REVERT — bench-best structure (55.2 us), locked in:
//  - 16 rows x 25 steps, 320 threads (5 clean waves), 2048 blocks (256CU x 8)
//  - 25-wide burst load per thread (MLP hides HBM/L3 latency)
//  - 2-barrier serial decayed scan (20 threads; cheap at this row count)
//  - phase B re-reads the window (L2/L3-hot; compiler rematerializes anyway)
//  - NT stores keep the 166 MB write stream from evicting x in L3
// Rounds 10-12 proved: algebraic re-read elimination (+2 us), flat lookback
// (+1 us), bigger OUT/ragged blocks (+9 us) all lose vs this point.
__global__ __launch_bounds__(NTHREADS, 3) void pcen_seg(
    const float* __restrict__ x,
    const float* __restrict__ weights,
    const float* __restrict__ alpha,
    const float* __restrict__ delta,
    const float* __restrict__ root,
    float* __restrict__ out)
{
    __shared__ float4 sP[NSUB][C4];   // 5 KB

    const int bid  = (int)blockIdx.x;
    const int b    = bid % B;
    const int kseg = bid / B;
    const int tid  = (int)threadIdx.x;
    const int g    = tid % C4;        // channel quad
    const int s    = tid / C4;        // row 0..15
    const int c    = g * 4;

    float4 w, q;
    {
        float wv;
        wv = clamp01(weights[c + 0]); w.x = wv; q.x = 1.0f - wv;
        wv = clamp01(weights[c + 1]); w.y = wv; q.y = 1.0f - wv;
        wv = clamp01(weights[c + 2]); w.z = wv; q.z = 1.0f - wv;
        wv = clamp01(weights[c + 3]); w.w = wv; q.w = 1.0f - wv;
    }

    const int t0 = kseg * SEG;
    const float4* xrow = reinterpret_cast<const float4*>(x + (size_t)b * T * C) + g;
    float4*       orow = reinterpret_cast<float4*>(out + (size_t)b * T * C) + g;

    const int ts = t0 - WARM * SUB + s * SUB;       // this row's window start
    const bool active = !(kseg == 0 && s < WARM);   // t<0 rows: partial = 0

    // ---- Burst-load the window (25 independent loads in flight) ----
    float4 xv[SUB];
    if (active) {
        #pragma unroll
        for (int t = 0; t < SUB; ++t)
            xv[t] = xrow[(ts + t) * C4];
    }

    // ---- Phase A: local EMA partial from the window ----
    float4 l = make_float4(0.f, 0.f, 0.f, 0.f);
    if (active) {
        if (kseg == 0 && s == WARM) l = xv[0];      // reference init e0 = x[:,0,:]
        #pragma unroll
        for (int t = 0; t < SUB; ++t) {
            float4 xvt = xv[t];
            l.x = fmaf(w.x, xvt.x, q.x * l.x);
            l.y = fmaf(w.y, xvt.y, q.y * l.y);
            l.z = fmaf(w.z, xvt.z, q.z * l.z);
            l.w = fmaf(w.w, xvt.w, q.w * l.w);
        }
    }
    sP[s][g] = l;

    // Hoisted per-channel params (overlap with barrier).
    float4 a, oor, d, dpow;
    {
        float av, rv, dv;
        av = fminf(alpha[c + 0], 1.0f); a.x = av;
        av = fminf(alpha[c + 1], 1.0f); a.y = av;
        av = fminf(alpha[c + 2], 1.0f); a.z = av;
        av = fminf(alpha[c + 3], 1.0f); a.w = av;
        rv = fmaxf(root[c + 0], 1.0f); oor.x = 1.0f / rv;
        rv = fmaxf(root[c + 1], 1.0f); oor.y = 1.0f / rv;
        rv = fmaxf(root[c + 2], 1.0f); oor.z = 1.0f / rv;
        rv = fmaxf(root[c + 3], 1.0f); oor.w = 1.0f / rv;
        dv = delta[c + 0]; d.x = dv; dpow.x = fexp2(oor.x * flog2(dv));
        dv = delta[c + 1]; d.y = dv; dpow.y = fexp2(oor.y * flog2(dv));
        dv = delta[c + 2]; d.z = dv; dpow.z = fexp2(oor.z * flog2(dv));
        dv = delta[c + 3]; d.w = dv; dpow.w = fexp2(oor.w * flog2(dv));
    }
    __syncthreads();

    // ---- Serial decayed prefix scan over 16 rows by the first 20 threads ----
    if (tid < C4) {
        float4 qq;
        {
            float wv;
            wv = clamp01(weights[tid * 4 + 0]); qq.x = 1.0f - wv;
            wv = clamp01(weights[tid * 4 + 1]); qq.y = 1.0f - wv;
            wv = clamp01(weights[tid * 4 + 2]); qq.z = 1.0f - wv;
            wv = clamp01(weights[tid * 4 + 3]); qq.w = 1.0f - wv;
        }
        float4 D;
        D.x = fexp2((float)SUB * flog2(qq.x));
        D.y = fexp2((float)SUB * flog2(qq.y));
        D.z = fexp2((float)SUB * flog2(qq.z));
        D.w = fexp2((float)SUB * flog2(qq.w));
        float4 y = make_float4(0.f, 0.f, 0.f, 0.f);
        for (int j = 0; j < NSUB; ++j) {
            float4 p = sP[j][tid];
            y.x = fmaf(D.x, y.x, p.x);
            y.y = fmaf(D.y, y.y, p.y);
            y.z = fmaf(D.z, y.z, p.z);
            y.w = fmaf(D.w, y.w, p.w);
            sP[j][tid] = y;
        }
    }
    __syncthreads();

    // ---- Phase B: output rows re-run EMA from carry + fused PCEN ----
    if (s < WARM) return;

    float4 e = sP[s - 1][g];                     // exclusive carry into this row
    if (kseg == 0 && s == WARM) e = xv[0];       // exact init for the t=0 row

    #pragma unroll
    for (int t = 0; t < SUB; ++t) {
        float4 xvt = xv[t];
        e.x = fmaf(w.x, xvt.x, q.x * e.x);
        e.y = fmaf(w.y, xvt.y, q.y * e.y);
        e.z = fmaf(w.z, xvt.z, q.z * e.z);
        e.w = fmaf(w.w, xvt.w, q.w * e.w);

        float4 o;
        float inner;
        inner = fmaf(xvt.x, fexp2(-a.x * flog2(FLOOR_EPS + e.x)), d.x);
        o.x = fexp2(oor.x * flog2(inner)) - dpow.x;
        inner = fmaf(xvt.y, fexp2(-a.y * flog2(FLOOR_EPS + e.y)), d.y);
        o.y = fexp2(oor.y * flog2(inner)) - dpow.y;
        inner = fmaf(xvt.z, fexp2(-a.z * flog2(FLOOR_EPS + e.z)), d.z);
        o.z = fexp2(oor.z * flog2(inner)) - dpow.z;
        inner = fmaf(xvt.w, fexp2(-a.w * flog2(FLOOR_EPS + e.w)), d.w);
        o.w = fexp2(oor.w * flog2(inner)) - dpow.w;

        // NT store: out is never re-read; keep L3 for x.
        union { float4 f4; f32x4 v; } u;
        u.f4 = o;
        __builtin_nontemporal_store(
            u.v, reinterpret_cast<f32x4*>(&orow[(ts + t) * C4]));
    }
}

extern "C" void kernel_launch(void* const* d_in, const int* in_sizes, int n_in,
                              void* d_out, int out_size, void* d_ws, size_t ws_size,
                              hipStream_t stream) {
    const float* x       = (const float*)d_in[0];
    const float* weights = (const float*)d_in[1];
    const float* alpha   = (const float*)d_in[2];
    const float* delta   = (const float*)d_in[3];
    const float* root    = (const float*)d_in[4];
    float* out = (float*)d_out;

    dim3 blk(NTHREADS);
    dim3 grd(NBLOCKS);
    pcen_seg<<<grd, blk, 0, stream>>>(x, weights, alpha, delta, root, out);
}